// Round 2
// baseline (373.347 us; speedup 1.0000x reference)
//
#include <hip/hip_runtime.h>
#include <hip/hip_bf16.h>
#include <hip/hip_fp16.h>

// Problem constants (fixed by the reference)
#define N_GENES_MAX 5000
#define N_ELEM_MAX  4000000
#define PARAMS_PER_GENE 445

// R11: per-BIN 16B records (one aligned dwordx4 per probe):
//   {l0 f32, w f32, lc f32, (rh f16 << 16) | lh f16}
// Walk tests are divide-free: down if x < l0, up if x >= l0 + w.
// This halves scattered-request count vs per-knot 8B pairs (theory: the
// eval kernels are bound by L2 scattered-request rate ~16/cy/XCD, not
// latency (ILP-4 null) and not BW (15% HBM)).
// Two-pass stage split retained (R9): pass A = stage0, pass B = stages 1+2.
// Midstate: uint2 {x' f32, (gene << 16) | lad0 f16} — 8B/elem coalesced.
__device__ uint4 g_b0[(size_t)N_GENES_MAX * 127];
__device__ uint4 g_b1[(size_t)N_GENES_MAX * 63];
__device__ uint4 g_b2[(size_t)N_GENES_MAX * 31];
__device__ uint2 g_mid[N_ELEM_MAX];

static __device__ __forceinline__ unsigned f2h(float f) {
    union { __half h; unsigned short u; } c;
    c.h = __float2half_rn(f);
    return (unsigned)c.u;
}
static __device__ __forceinline__ float h2f(unsigned u) {
    union { unsigned short u; __half h; } c;
    c.u = (unsigned short)u;
    return __half2float(c.h);
}

// ---- wave-level primitives (64 lanes) ----
static __device__ __forceinline__ float wscan_incl(float v) {
    const int lane = threadIdx.x & 63;
    #pragma unroll
    for (int off = 1; off < 64; off <<= 1) {
        float u = __shfl_up(v, off, 64);
        if (lane >= off) v += u;
    }
    return v;
}
static __device__ __forceinline__ float wmax64(float v) {
    #pragma unroll
    for (int off = 32; off > 0; off >>= 1) v = fmaxf(v, __shfl_xor(v, off, 64));
    return v;
}
static __device__ __forceinline__ float wsum64(float v) {
    #pragma unroll
    for (int off = 32; off > 0; off >>= 1) v += __shfl_xor(v, off, 64);
    return v;
}

// ---------------------------------------------------------------------------
// Kernel 1: build per-(gene,stage) bin records. grid=(G,3), block=128.
// (R8-verified scan logic; output format changed to per-bin 16B.)
// ---------------------------------------------------------------------------
__global__ void build_knots(const float* __restrict__ params) {
    const int g = blockIdx.x;
    const int t = blockIdx.y;
    const int ns[3]   = {128, 64, 32};
    const int poff[3] = {0, 255, 382};

    const int n = ns[t];
    const int m = n - 1;
    const float* ph = params + (size_t)g * PARAMS_PER_GENE + poff[t];
    const float* pw = ph + n;

    __shared__ float s2[2];
    __shared__ float s_scan[128];
    __shared__ float s_h[129];
    __shared__ float s_loc[129];
    __shared__ float s_cdf[128];

    const int tid  = threadIdx.x;
    const int lane = tid & 63;
    const int wv   = tid >> 6;

    const float uw = (tid < m) ? pw[tid] : -1e30f;
    float vmax = wmax64(uw);
    if (lane == 0) s2[wv] = vmax;
    __syncthreads();
    const float mx = fmaxf(s2[0], s2[1]);
    __syncthreads();

    const float e = (tid < m) ? __expf(uw - mx) : 0.0f;

    float sc = wscan_incl(e);
    if (lane == 63) s2[wv] = sc;
    __syncthreads();
    if (wv == 1) sc += s2[0];
    s_scan[tid] = sc;
    __syncthreads();

    const float S = s_scan[m - 1];
    const float invS = 1.0f / S;
    if (tid == 0) s_loc[0] = 0.0f;
    if (tid < m) s_loc[tid + 1] = (tid == m - 1) ? 1.0f : s_scan[tid] * invS;
    const float w_i = e * invS;

    const float eh = (tid < n) ? __expf(ph[tid]) : 0.0f;
    s_h[tid] = eh;
    if (tid == 0) s_h[128] = 0.0f;
    __syncthreads();

    const float term = (tid < m) ? 0.5f * (s_h[tid] + s_h[tid + 1]) * w_i : 0.0f;
    float ts = wsum64(term);
    if (lane == 0) s2[wv] = ts;
    __syncthreads();
    const float area = s2[0] + s2[1];
    __syncthreads();

    const float ia = 1.0f / area;

    float c = wscan_incl(term * ia);
    if (lane == 63) s2[wv] = c;
    __syncthreads();
    if (wv == 1) c += s2[0];
    s_scan[tid] = c;
    __syncthreads();

    if (tid == 0) s_cdf[0] = 0.0f;
    if (tid < m) s_cdf[tid + 1] = (tid == m - 1) ? 1.0f : s_scan[tid];
    __syncthreads();

    if (tid < m) {
        const float l0 = s_loc[tid];
        const float w  = s_loc[tid + 1] - l0;
        uint4 r;
        r.x = __float_as_uint(l0);
        r.y = __float_as_uint(w);
        r.z = __float_as_uint(s_cdf[tid]);
        r.w = (f2h(s_h[tid + 1] * ia) << 16) | f2h(s_h[tid] * ia);
        if (t == 0)      g_b0[(size_t)g * 127 + tid] = r;
        else if (t == 1) g_b1[(size_t)g * 63 + tid] = r;
        else             g_b2[(size_t)g * 31 + tid] = r;
    }
}

// ---------------------------------------------------------------------------
// Stage evaluation: ONE aligned 16B load per probe (and per walk step).
// K = knot count; bins = K-1 records.
// ---------------------------------------------------------------------------
template <int K>
static __device__ __forceinline__ void stage(const uint4* __restrict__ bins,
                                             float& x, float& lad) {
    int b = (int)(x * (float)(K - 1));
    b = (b < 0) ? 0 : ((b > K - 2) ? K - 2 : b);
    uint4 r = bins[b];
    float l0 = __uint_as_float(r.x);
    float w  = __uint_as_float(r.y);
    while (b > 0 && l0 > x) {
        --b;
        r = bins[b];
        l0 = __uint_as_float(r.x);
        w  = __uint_as_float(r.y);
    }
    while (b < K - 2 && l0 + w <= x) {
        ++b;
        r = bins[b];
        l0 = __uint_as_float(r.x);
        w  = __uint_as_float(r.y);
    }
    const float lh = h2f(r.w & 0xffffu);
    const float rh = h2f(r.w >> 16);
    const float lc = __uint_as_float(r.z);
    const float alpha = (x - l0) / w;
    float o = (0.5f * (rh - lh) * w) * alpha * alpha + (lh * w) * alpha + lc;
    o = fminf(fmaxf(o, 0.0f), 1.0f);
    lad += __logf(alpha * (rh - lh) + lh);
    x = o;
}

typedef float fvec2 __attribute__((ext_vector_type(2)));
typedef int   ivec2 __attribute__((ext_vector_type(2)));
typedef unsigned uvec4 __attribute__((ext_vector_type(4)));

// ---------------------------------------------------------------------------
// Kernel 2a: pass A — stage0 only. 2 elems/thread (R10's ILP-4 was null).
// ---------------------------------------------------------------------------
__global__ void spline_evalA(const float* __restrict__ x_in,
                             const int* __restrict__ gix, int N) {
    const int i = blockIdx.x * blockDim.x + threadIdx.x;
    const int i2 = i * 2;
    if (i2 + 1 < N) {
        const fvec2 xv = __builtin_nontemporal_load((const fvec2*)(x_in + i2));
        const ivec2 gv = __builtin_nontemporal_load((const ivec2*)(gix + i2));
        float x0 = xv.x, x1 = xv.y;
        float l0 = 0.0f, l1 = 0.0f;
        stage<128>(g_b0 + (size_t)gv.x * 127, x0, l0);
        stage<128>(g_b0 + (size_t)gv.y * 127, x1, l1);
        uvec4 mid;
        mid.x = __float_as_uint(x0);
        mid.y = ((unsigned)gv.x << 16) | f2h(l0);
        mid.z = __float_as_uint(x1);
        mid.w = ((unsigned)gv.y << 16) | f2h(l1);
        __builtin_nontemporal_store(mid, (uvec4*)(g_mid + i2));
    } else if (i2 < N) {
        float x0 = x_in[i2];
        float l0 = 0.0f;
        const int g = gix[i2];
        stage<128>(g_b0 + (size_t)g * 127, x0, l0);
        uint2 m;
        m.x = __float_as_uint(x0);
        m.y = ((unsigned)g << 16) | f2h(l0);
        g_mid[i2] = m;
    }
}

// ---------------------------------------------------------------------------
// Kernel 2b: pass B — stages 1+2. 2 elems/thread.
// ---------------------------------------------------------------------------
__global__ void spline_evalB(float* __restrict__ out, int N) {
    const int i = blockIdx.x * blockDim.x + threadIdx.x;
    const int i2 = i * 2;
    if (i2 + 1 < N) {
        const uvec4 mid = __builtin_nontemporal_load((const uvec4*)(g_mid + i2));
        float x0 = __uint_as_float(mid.x);
        float x1 = __uint_as_float(mid.z);
        const int g0 = (int)(mid.y >> 16);
        const int g1 = (int)(mid.w >> 16);
        float l0 = h2f(mid.y & 0xffffu);
        float l1 = h2f(mid.w & 0xffffu);
        stage<64>(g_b1 + (size_t)g0 * 63, x0, l0);
        stage<64>(g_b1 + (size_t)g1 * 63, x1, l1);
        stage<32>(g_b2 + (size_t)g0 * 31, x0, l0);
        stage<32>(g_b2 + (size_t)g1 * 31, x1, l1);
        fvec2 o0; o0.x = x0; o0.y = x1;
        fvec2 o1; o1.x = l0; o1.y = l1;
        __builtin_nontemporal_store(o0, (fvec2*)(out + i2));
        __builtin_nontemporal_store(o1, (fvec2*)(out + N + i2));
    } else if (i2 < N) {
        const uint2 mid = g_mid[i2];
        float x0 = __uint_as_float(mid.x);
        const int g0 = (int)(mid.y >> 16);
        float l0 = h2f(mid.y & 0xffffu);
        stage<64>(g_b1 + (size_t)g0 * 63, x0, l0);
        stage<32>(g_b2 + (size_t)g0 * 31, x0, l0);
        out[i2] = x0;
        out[N + i2] = l0;
    }
}

// ---------------------------------------------------------------------------
extern "C" void kernel_launch(void* const* d_in, const int* in_sizes, int n_in,
                              void* d_out, int out_size, void* d_ws, size_t ws_size,
                              hipStream_t stream) {
    const float* x      = (const float*)d_in[0];
    const int*   gix    = (const int*)d_in[1];
    const float* params = (const float*)d_in[2];
    float* out = (float*)d_out;

    const int N = in_sizes[0];
    const int G = in_sizes[2] / PARAMS_PER_GENE;

    build_knots<<<dim3(G, 3), 128, 0, stream>>>(params);

    const int block = 256;
    const int nh = (N + 1) / 2;
    const int grid = (nh + block - 1) / block;
    spline_evalA<<<grid, block, 0, stream>>>(x, gix, N);
    spline_evalB<<<grid, block, 0, stream>>>(out, N);
}